// Round 15
// baseline (197.598 us; speedup 1.0000x reference)
//
#include <hip/hip_runtime.h>

#define N_NODES 100000
#define N_EDGES 3200000
#define F_IN    128
#define H_DIM   32
#define B_GR    256
#define NEG     0.2f

#define FBIN_SZ  50
#define N_FBIN   (N_NODES / FBIN_SZ)        // 2000
#define BIN_CAP  2048                        // mean 1600, +11 sigma
#define CPAD     16                          // bcnt 64B padding
#define PART_T   1024
#define EPB_R    4                           // int4 rounds per thread
#define EPB_G    (PART_T * EPB_R)            // 4096 int4 groups = 16384 edges/block
#define PART_NBLK ((N_EDGES / 4 + EPB_G - 1) / EPB_G)   // 196
#define LIN_BLK  ((N_NODES + 63) / 64)       // 1563 (64 nodes/block)

// ---- monotonic float<->uint encoding for atomicMax on floats ----
__device__ __forceinline__ unsigned fenc(float f) {
    unsigned u = __float_as_uint(f);
    return (u & 0x80000000u) ? ~u : (u | 0x80000000u);
}
__device__ __forceinline__ float fdec(unsigned u) {
    return (u & 0x80000000u) ? __uint_as_float(u & 0x7FFFFFFFu)
                             : __uint_as_float(~u);
}

// K1: fat kernel. Blocks [0, PART_NBLK): two-pass edge binning, 16384
// edges/block; pass1 reads dst only -> LDS hist (2000 bins); one global
// atomic per touched bin; pass2 re-reads ei (L2-hot) and direct-writes.
// Blocks [PART_NBLK, +LIN_BLK): xl = x@Wl, xr = x@Wr as 4 x 256-thread
// quarters sharing W tiles. Independent -> co-scheduled in one dispatch.
__global__ __launch_bounds__(1024) void k_fused(
    const int* __restrict__ ei, int* __restrict__ bcnt, unsigned* __restrict__ binbuf,
    const float* __restrict__ x, const float* __restrict__ Wl,
    const float* __restrict__ Wr, float* __restrict__ xl, float* __restrict__ xr)
{
    __shared__ __align__(16) float smem[16384];   // 64 KB union
    int t = threadIdx.x;

    if (blockIdx.x < PART_NBLK) {
        // ---------------- edge binning (two-pass, re-read) ----------------
        int* lcnt = (int*)smem;           // 2048 ints (2000 used)
        int* cur  = lcnt + 2048;          // 2048 ints
        lcnt[t] = 0; lcnt[t + 1024] = 0;
        __syncthreads();
        int g0 = blockIdx.x * EPB_G;
        const int4* dsrc = (const int4*)(ei + N_EDGES);
        const int4* ssrc = (const int4*)ei;
        #pragma unroll
        for (int r = 0; r < EPB_R; ++r) {
            int i = g0 + r * PART_T + t;
            if (i < N_EDGES / 4) {
                int4 d = dsrc[i];
                atomicAdd(&lcnt[d.x / FBIN_SZ], 1);
                atomicAdd(&lcnt[d.y / FBIN_SZ], 1);
                atomicAdd(&lcnt[d.z / FBIN_SZ], 1);
                atomicAdd(&lcnt[d.w / FBIN_SZ], 1);
            }
        }
        __syncthreads();
        for (int b = t; b < N_FBIN; b += PART_T) {
            int c = lcnt[b];
            if (c > 0) cur[b] = atomicAdd(&bcnt[b * CPAD], c);
        }
        __syncthreads();
        #pragma unroll
        for (int r = 0; r < EPB_R; ++r) {
            int i = g0 + r * PART_T + t;
            if (i < N_EDGES / 4) {
                int4 s = ssrc[i];
                int4 d = dsrc[i];
                int b, p;
                b = d.x / FBIN_SZ; p = atomicAdd(&cur[b], 1);
                binbuf[(size_t)b * BIN_CAP + p] = ((unsigned)(d.x - b * FBIN_SZ) << 17) | (unsigned)s.x;
                b = d.y / FBIN_SZ; p = atomicAdd(&cur[b], 1);
                binbuf[(size_t)b * BIN_CAP + p] = ((unsigned)(d.y - b * FBIN_SZ) << 17) | (unsigned)s.y;
                b = d.z / FBIN_SZ; p = atomicAdd(&cur[b], 1);
                binbuf[(size_t)b * BIN_CAP + p] = ((unsigned)(d.z - b * FBIN_SZ) << 17) | (unsigned)s.z;
                b = d.w / FBIN_SZ; p = atomicAdd(&cur[b], 1);
                binbuf[(size_t)b * BIN_CAP + p] = ((unsigned)(d.w - b * FBIN_SZ) << 17) | (unsigned)s.w;
            }
        }
    } else {
        // ---------------- linear: xl/xr ----------------
        float* Wls = smem;            // 4096
        float* Wrs = smem + 4096;     // 4096
        float* xsb = smem + 8192;     // 4 x 2048
        int blk = blockIdx.x - PART_NBLK;
        for (int i = t; i < F_IN * H_DIM; i += 1024) { Wls[i] = Wl[i]; Wrs[i] = Wr[i]; }
        int q = t >> 8, tq = t & 255;
        size_t base = (size_t)blk * 64 + q * 16;
        bool act = base < N_NODES;     // quarters are 16-aligned; all-or-nothing
        float* xs = xsb + q * 2048;
        if (act) {
            const float4* xg = (const float4*)(x + base * F_IN);
            float4* xs4 = (float4*)xs;
            xs4[tq] = xg[tq];
            xs4[tq + 256] = xg[tq + 256];
        }
        __syncthreads();
        if (act) {
            int nl = tq >> 5, h = tq & 31;
            float al0 = 0.f, ar0 = 0.f, al1 = 0.f, ar1 = 0.f;
            const float4* xa4 = (const float4*)(xs + nl * F_IN);
            const float4* xb4 = (const float4*)(xs + (nl + 8) * F_IN);
            #pragma unroll 8
            for (int f4 = 0; f4 < 32; ++f4) {
                float4 xa = xa4[f4], xb = xb4[f4];
                int fb = f4 * 4;
                float w;
                w = Wls[(fb + 0) * 32 + h]; al0 = fmaf(xa.x, w, al0); al1 = fmaf(xb.x, w, al1);
                w = Wls[(fb + 1) * 32 + h]; al0 = fmaf(xa.y, w, al0); al1 = fmaf(xb.y, w, al1);
                w = Wls[(fb + 2) * 32 + h]; al0 = fmaf(xa.z, w, al0); al1 = fmaf(xb.z, w, al1);
                w = Wls[(fb + 3) * 32 + h]; al0 = fmaf(xa.w, w, al0); al1 = fmaf(xb.w, w, al1);
                w = Wrs[(fb + 0) * 32 + h]; ar0 = fmaf(xa.x, w, ar0); ar1 = fmaf(xb.x, w, ar1);
                w = Wrs[(fb + 1) * 32 + h]; ar0 = fmaf(xa.y, w, ar0); ar1 = fmaf(xb.y, w, ar1);
                w = Wrs[(fb + 2) * 32 + h]; ar0 = fmaf(xa.z, w, ar0); ar1 = fmaf(xb.z, w, ar1);
                w = Wrs[(fb + 3) * 32 + h]; ar0 = fmaf(xa.w, w, ar0); ar1 = fmaf(xb.w, w, ar1);
            }
            size_t n0 = base + nl, n1 = base + nl + 8;
            xl[n0 * 32 + h] = al0; xr[n0 * 32 + h] = ar0;
            xl[n1 * 32 + h] = al1; xr[n1 * 32 + h] = ar1;
        }
    }
}

// K2: per-bin in-LDS CSR build + fused score/softmax/aggregate/pool.
// Block = one bin (50 dst nodes, <=2048 edges). Small LDS (8.5 KB) ->
// thread-limit occupancy (4 blocks/CU). Phase 2: half-wave = node, two
// 16-lane streams, lane = h-pair (float2), 2-deep unroll per stream.
__global__ __launch_bounds__(512) void k_aggregate(
    const unsigned* __restrict__ binbuf, const int* __restrict__ bcnt,
    const float* __restrict__ xl, const float* __restrict__ xr,
    const float* __restrict__ att, const float* __restrict__ bias,
    const int* __restrict__ batch, unsigned* __restrict__ gu)
{
    __shared__ unsigned eL[BIN_CAP];      // 8 KB sorted edge list
    __shared__ int cnt[64];
    __shared__ int sc[64];
    __shared__ int cur[64];
    __shared__ unsigned lmax[64];         // bin spans <= 2 graphs (50 < 390)
    int t = threadIdx.x;
    int bin = blockIdx.x;
    int n_e = bcnt[bin * CPAD];
    const unsigned* bb = binbuf + (size_t)bin * BIN_CAP;

    if (t < 64) { cnt[t] = 0; lmax[t] = 0u; }
    __syncthreads();
    for (int i = t; i < n_e; i += 512)
        atomicAdd(&cnt[bb[i] >> 17], 1);
    __syncthreads();
    if (t < 64) sc[t] = cnt[t];
    __syncthreads();
    for (int off = 1; off < 64; off <<= 1) {    // inclusive scan over 64
        int v = 0;
        if (t < 64 && t >= off) v = sc[t - off];
        __syncthreads();
        if (t < 64) sc[t] += v;
        __syncthreads();
    }
    if (t < 64) cur[t] = sc[t] - cnt[t];
    __syncthreads();
    for (int i = t; i < n_e; i += 512) {
        unsigned u = bb[i];
        int p = atomicAdd(&cur[u >> 17], 1);
        eL[p] = u;
    }
    __syncthreads();

    int lane = t & 63;
    int wv = t >> 6;
    int half = lane >> 5;
    int gid = (lane >> 4) & 1;
    int hp = lane & 15;
    const float2 a2 = ((const float2*)att)[hp];
    const float2 b2 = ((const float2*)bias)[hp];
    int lg0 = batch[bin * FBIN_SZ];

    for (int nl = wv * 2 + half; nl < FBIN_SZ; nl += 16) {
        int n = bin * FBIN_SZ + nl;
        int e0 = (nl > 0) ? sc[nl - 1] : 0;
        int e1 = sc[nl];
        const float2 xr2 = ((const float2*)(xr + (size_t)n * H_DIM))[hp];
        const float2 xl2 = ((const float2*)(xl + (size_t)n * H_DIM))[hp];

        float vx = xl2.x + xr2.x; vx = fmaxf(vx, vx * NEG);
        float vy = xl2.y + xr2.y; vy = fmaxf(vy, vy * NEG);
        float pr = vx * a2.x; pr = fmaf(vy, a2.y, pr);
        pr += __shfl_xor(pr, 1); pr += __shfl_xor(pr, 2);
        pr += __shfl_xor(pr, 4); pr += __shfl_xor(pr, 8);
        float z = 0.f; float2 acc = make_float2(0.f, 0.f);
        if (gid == 0) {
            float p = __expf(fminf(pr, 70.f));
            z = p; acc.x = p * xl2.x; acc.y = p * xl2.y;
        }

        int j = e0 + gid;
        for (; j + 2 < e1; j += 4) {          // 2-deep unroll per stream
            unsigned uA = eL[j], uB = eL[j + 2];
            int sA = (int)(uA & 0x1FFFFu), sB = (int)(uB & 0x1FFFFu);
            float2 xA = ((const float2*)(xl + (size_t)sA * H_DIM))[hp];
            float2 xB = ((const float2*)(xl + (size_t)sB * H_DIM))[hp];
            float ax = xA.x + xr2.x; ax = fmaxf(ax, ax * NEG);
            float ay = xA.y + xr2.y; ay = fmaxf(ay, ay * NEG);
            float bx = xB.x + xr2.x; bx = fmaxf(bx, bx * NEG);
            float by = xB.y + xr2.y; by = fmaxf(by, by * NEG);
            float pA = ax * a2.x; pA = fmaf(ay, a2.y, pA);
            float pB = bx * a2.x; pB = fmaf(by, a2.y, pB);
            pA += __shfl_xor(pA, 1); pB += __shfl_xor(pB, 1);
            pA += __shfl_xor(pA, 2); pB += __shfl_xor(pB, 2);
            pA += __shfl_xor(pA, 4); pB += __shfl_xor(pB, 4);
            pA += __shfl_xor(pA, 8); pB += __shfl_xor(pB, 8);
            float eA = __expf(fminf(pA, 70.f));
            float eB = __expf(fminf(pB, 70.f));
            z += eA + eB;
            acc.x = fmaf(eA, xA.x, acc.x); acc.y = fmaf(eA, xA.y, acc.y);
            acc.x = fmaf(eB, xB.x, acc.x); acc.y = fmaf(eB, xB.y, acc.y);
        }
        for (; j < e1; j += 2) {
            unsigned u = eL[j];
            int s = (int)(u & 0x1FFFFu);
            float2 xs2 = ((const float2*)(xl + (size_t)s * H_DIM))[hp];
            float ex = xs2.x + xr2.x; ex = fmaxf(ex, ex * NEG);
            float ey = xs2.y + xr2.y; ey = fmaxf(ey, ey * NEG);
            float pp = ex * a2.x; pp = fmaf(ey, a2.y, pp);
            pp += __shfl_xor(pp, 1); pp += __shfl_xor(pp, 2);
            pp += __shfl_xor(pp, 4); pp += __shfl_xor(pp, 8);
            float p = __expf(fminf(pp, 70.f));
            z += p;
            acc.x = fmaf(p, xs2.x, acc.x);
            acc.y = fmaf(p, xs2.y, acc.y);
        }

        z += __shfl_xor(z, 16);
        acc.x += __shfl_xor(acc.x, 16);
        acc.y += __shfl_xor(acc.y, 16);

        if (gid == 0) {
            float inv = 1.f / z;
            float ox = fmaf(acc.x, inv, b2.x);
            float oy = fmaf(acc.y, inv, b2.y);
            int gi = batch[n] - lg0;
            atomicMax(&lmax[gi * 32 + hp * 2 + 0], fenc(ox));
            atomicMax(&lmax[gi * 32 + hp * 2 + 1], fenc(oy));
        }
    }
    __syncthreads();
    if (t < 64) {
        int g = lg0 + (t >> 5);
        int glast = batch[bin * FBIN_SZ + FBIN_SZ - 1];
        if (g <= glast) atomicMax(&gu[g * H_DIM + (t & 31)], lmax[t]);
    }
}

// K3: MLP head, one graph per block (256 blocks), h1/h2 in LDS, 4-way
// K-slice ILP in the W2 stage.
__global__ __launch_bounds__(512) void k_head(
    const unsigned* __restrict__ gu, const float* __restrict__ W1,
    const float* __restrict__ b1, const float* __restrict__ W2,
    const float* __restrict__ b2, const float* __restrict__ W3,
    const float* __restrict__ b3, float* __restrict__ out)
{
    __shared__ float gs[H_DIM];
    __shared__ float h1s[1024];
    __shared__ float h2s[512];
    int b = blockIdx.x, t = threadIdx.x;
    if (t < H_DIM) gs[t] = fdec(gu[b * H_DIM + t]);
    __syncthreads();
    #pragma unroll
    for (int jj = 0; jj < 2; ++jj) {        // h1: 1024 cols
        int j = jj * 512 + t;
        float a = b1[j];
        #pragma unroll
        for (int k = 0; k < H_DIM; ++k) a = fmaf(gs[k], W1[k * 1024 + j], a);
        h1s[j] = fmaxf(a, 0.f);
    }
    __syncthreads();
    {                                        // h2: 512 cols, 4 K-slices ILP
        float a0 = 0.f, a1 = 0.f, a2 = 0.f, a3 = 0.f;
        #pragma unroll 4
        for (int k = 0; k < 256; ++k) {
            a0 = fmaf(h1s[k      ], W2[(size_t)(k      ) * 512 + t], a0);
            a1 = fmaf(h1s[k + 256], W2[(size_t)(k + 256) * 512 + t], a1);
            a2 = fmaf(h1s[k + 512], W2[(size_t)(k + 512) * 512 + t], a2);
            a3 = fmaf(h1s[k + 768], W2[(size_t)(k + 768) * 512 + t], a3);
        }
        h2s[t] = fmaxf((a0 + a1) + (a2 + a3) + b2[t], 0.f);
    }
    __syncthreads();
    if (t < 256) {                           // out: 4 classes x 64 lanes
        int c = t >> 6, lane = t & 63;
        float a = 0.f;
        #pragma unroll
        for (int k = lane; k < 512; k += 64)
            a = fmaf(h2s[k], W3[k * 4 + c], a);
        for (int off = 32; off; off >>= 1) a += __shfl_down(a, off);
        if (lane == 0) out[b * 4 + c] = a + b3[c];
    }
}

extern "C" void kernel_launch(void* const* d_in, const int* in_sizes, int n_in,
                              void* d_out, int out_size, void* d_ws, size_t ws_size,
                              hipStream_t stream)
{
    const float* x     = (const float*)d_in[0];
    const int*   ei    = (const int*)d_in[1];
    const int*   batch = (const int*)d_in[2];
    const float* Wl    = (const float*)d_in[3];
    const float* Wr    = (const float*)d_in[4];
    const float* att   = (const float*)d_in[5];
    const float* bias  = (const float*)d_in[6];
    const float* W1    = (const float*)d_in[7];
    const float* b1    = (const float*)d_in[8];
    const float* W2    = (const float*)d_in[9];
    const float* b2    = (const float*)d_in[10];
    const float* W3    = (const float*)d_in[11];
    const float* b3    = (const float*)d_in[12];
    float* out = (float*)d_out;

    // workspace layout (~42 MB)
    float*    xl     = (float*)d_ws;                               // 3.2M f
    float*    xr     = xl + (size_t)N_NODES * H_DIM;               // 3.2M f
    unsigned* binbuf = (unsigned*)(xr + (size_t)N_NODES * H_DIM);  // 2000*2048
    int*      bcnt   = (int*)(binbuf + (size_t)N_FBIN * BIN_CAP);  // 32000 [memset]
    unsigned* gu     = (unsigned*)(bcnt + N_FBIN * CPAD);          // 8192  [memset]

    hipMemsetAsync(bcnt, 0, (size_t)(N_FBIN * CPAD + B_GR * H_DIM) * sizeof(int), stream);

    k_fused<<<PART_NBLK + LIN_BLK, 1024, 0, stream>>>(
        ei, bcnt, binbuf, x, Wl, Wr, xl, xr);
    k_aggregate<<<N_FBIN, 512, 0, stream>>>(binbuf, bcnt, xl, xr, att, bias, batch, gu);
    k_head<<<B_GR, 512, 0, stream>>>(gu, W1, b1, W2, b2, W3, b3, out);
}

// Round 16
// 169.311 us; speedup vs baseline: 1.1671x; 1.1671x over previous
//
#include <hip/hip_runtime.h>
#include <hip/hip_fp16.h>

#define N_NODES 100000
#define N_EDGES 3200000
#define F_IN    128
#define H_DIM   32
#define B_GR    256
#define NEG     0.2f

#define FBIN_SZ  100
#define N_FBIN   (N_NODES / FBIN_SZ)        // 1000
#define BIN_CAP  4096                        // mean 3200, +15.8 sigma
#define CPAD     16                          // bcnt 64B padding
#define PART_T   1024
#define EPB_R    8                           // int4 rounds per thread (re-read, no reg cache)
#define EPB_G    (PART_T * EPB_R)            // 32768 edges/block
#define PART_NBLK ((N_EDGES / 4 + EPB_G - 1) / EPB_G)   // 98
#define LIN_BLK  ((N_NODES + 63) / 64)       // 1563 (64 nodes/block)

// ---- monotonic float<->uint encoding for atomicMax on floats ----
__device__ __forceinline__ unsigned fenc(float f) {
    unsigned u = __float_as_uint(f);
    return (u & 0x80000000u) ? ~u : (u | 0x80000000u);
}
__device__ __forceinline__ float fdec(unsigned u) {
    return (u & 0x80000000u) ? __uint_as_float(u & 0x7FFFFFFFu)
                             : __uint_as_float(~u);
}

// K1: fat kernel. Blocks [0, PART_NBLK): two-pass edge binning (32768
// edges/block; pass1 reads dst only -> LDS hist; one global atomic per
// touched bin; pass2 re-reads ei (L2-hot), direct-writes ~full-line runs).
// Blocks [PART_NBLK, +LIN_BLK): xl16 = fp16(x@Wl), xr = x@Wr as
// 4 x 256-thread quarters sharing W tiles. Independent -> co-scheduled.
__global__ __launch_bounds__(1024) void k_fused(
    const int* __restrict__ ei, int* __restrict__ bcnt, unsigned* __restrict__ binbuf,
    const float* __restrict__ x, const float* __restrict__ Wl,
    const float* __restrict__ Wr, __half* __restrict__ xl16, float* __restrict__ xr)
{
    __shared__ __align__(16) float smem[16384];   // 64 KB union
    int t = threadIdx.x;

    if (blockIdx.x < PART_NBLK) {
        // ---------------- edge binning (two-pass, re-read) ----------------
        int* lcnt = (int*)smem;           // 1024 ints (1000 used)
        int* cur  = lcnt + 1024;          // 1024 ints
        lcnt[t] = 0;
        __syncthreads();
        int g0 = blockIdx.x * EPB_G;
        const int4* dsrc = (const int4*)(ei + N_EDGES);
        const int4* ssrc = (const int4*)ei;
        #pragma unroll
        for (int r = 0; r < EPB_R; ++r) {
            int i = g0 + r * PART_T + t;
            if (i < N_EDGES / 4) {
                int4 d = dsrc[i];
                atomicAdd(&lcnt[d.x / FBIN_SZ], 1);
                atomicAdd(&lcnt[d.y / FBIN_SZ], 1);
                atomicAdd(&lcnt[d.z / FBIN_SZ], 1);
                atomicAdd(&lcnt[d.w / FBIN_SZ], 1);
            }
        }
        __syncthreads();
        if (t < N_FBIN) {
            int c = lcnt[t];
            if (c > 0) cur[t] = atomicAdd(&bcnt[t * CPAD], c);
        }
        __syncthreads();
        #pragma unroll
        for (int r = 0; r < EPB_R; ++r) {
            int i = g0 + r * PART_T + t;
            if (i < N_EDGES / 4) {
                int4 s = ssrc[i];
                int4 d = dsrc[i];
                int b, p;
                b = d.x / FBIN_SZ; p = atomicAdd(&cur[b], 1);
                binbuf[(size_t)b * BIN_CAP + p] = ((unsigned)(d.x - b * FBIN_SZ) << 17) | (unsigned)s.x;
                b = d.y / FBIN_SZ; p = atomicAdd(&cur[b], 1);
                binbuf[(size_t)b * BIN_CAP + p] = ((unsigned)(d.y - b * FBIN_SZ) << 17) | (unsigned)s.y;
                b = d.z / FBIN_SZ; p = atomicAdd(&cur[b], 1);
                binbuf[(size_t)b * BIN_CAP + p] = ((unsigned)(d.z - b * FBIN_SZ) << 17) | (unsigned)s.z;
                b = d.w / FBIN_SZ; p = atomicAdd(&cur[b], 1);
                binbuf[(size_t)b * BIN_CAP + p] = ((unsigned)(d.w - b * FBIN_SZ) << 17) | (unsigned)s.w;
            }
        }
    } else {
        // ---------------- linear: xl16/xr ----------------
        float* Wls = smem;            // 4096
        float* Wrs = smem + 4096;     // 4096
        float* xsb = smem + 8192;     // 4 x 2048
        int blk = blockIdx.x - PART_NBLK;
        for (int i = t; i < F_IN * H_DIM; i += 1024) { Wls[i] = Wl[i]; Wrs[i] = Wr[i]; }
        int q = t >> 8, tq = t & 255;
        size_t base = (size_t)blk * 64 + q * 16;
        bool act = base < N_NODES;     // quarters are 16-aligned; all-or-nothing
        float* xs = xsb + q * 2048;
        if (act) {
            const float4* xg = (const float4*)(x + base * F_IN);
            float4* xs4 = (float4*)xs;
            xs4[tq] = xg[tq];
            xs4[tq + 256] = xg[tq + 256];
        }
        __syncthreads();
        if (act) {
            int nl = tq >> 5, h = tq & 31;
            float al0 = 0.f, ar0 = 0.f, al1 = 0.f, ar1 = 0.f;
            const float4* xa4 = (const float4*)(xs + nl * F_IN);
            const float4* xb4 = (const float4*)(xs + (nl + 8) * F_IN);
            #pragma unroll 8
            for (int f4 = 0; f4 < 32; ++f4) {
                float4 xa = xa4[f4], xb = xb4[f4];
                int fb = f4 * 4;
                float w;
                w = Wls[(fb + 0) * 32 + h]; al0 = fmaf(xa.x, w, al0); al1 = fmaf(xb.x, w, al1);
                w = Wls[(fb + 1) * 32 + h]; al0 = fmaf(xa.y, w, al0); al1 = fmaf(xb.y, w, al1);
                w = Wls[(fb + 2) * 32 + h]; al0 = fmaf(xa.z, w, al0); al1 = fmaf(xb.z, w, al1);
                w = Wls[(fb + 3) * 32 + h]; al0 = fmaf(xa.w, w, al0); al1 = fmaf(xb.w, w, al1);
                w = Wrs[(fb + 0) * 32 + h]; ar0 = fmaf(xa.x, w, ar0); ar1 = fmaf(xb.x, w, ar1);
                w = Wrs[(fb + 1) * 32 + h]; ar0 = fmaf(xa.y, w, ar0); ar1 = fmaf(xb.y, w, ar1);
                w = Wrs[(fb + 2) * 32 + h]; ar0 = fmaf(xa.z, w, ar0); ar1 = fmaf(xb.z, w, ar1);
                w = Wrs[(fb + 3) * 32 + h]; ar0 = fmaf(xa.w, w, ar0); ar1 = fmaf(xb.w, w, ar1);
            }
            size_t n0 = base + nl, n1 = base + nl + 8;
            xl16[n0 * 32 + h] = __float2half(al0); xr[n0 * 32 + h] = ar0;
            xl16[n1 * 32 + h] = __float2half(al1); xr[n1 * 32 + h] = ar1;
        }
    }
}

// K2: per-bin in-LDS CSR build + fused score/softmax/aggregate/pool.
// Block = one bin (100 dst nodes, <=4096 edges). Phase 2: half-wave = node,
// two 16-lane streams, lane = h-pair; xl gathered as fp16 (half2 -> 64B/row,
// L2-resident working set), converted to f32 in-register. 2-deep unroll.
__global__ __launch_bounds__(512) void k_aggregate(
    const unsigned* __restrict__ binbuf, const int* __restrict__ bcnt,
    const __half* __restrict__ xl16, const float* __restrict__ xr,
    const float* __restrict__ att, const float* __restrict__ bias,
    const int* __restrict__ batch, unsigned* __restrict__ gu)
{
    __shared__ unsigned eL[BIN_CAP];      // 16 KB sorted edge list
    __shared__ int cnt[128];
    __shared__ int sc[128];
    __shared__ int cur[128];
    __shared__ unsigned lmax[64];         // bin spans <= 2 graphs (100 < 390)
    int t = threadIdx.x;
    int bin = blockIdx.x;
    int n_e = bcnt[bin * CPAD];
    const unsigned* bb = binbuf + (size_t)bin * BIN_CAP;

    if (t < 128) cnt[t] = 0;
    if (t < 64) lmax[t] = 0u;             // encodes -inf
    __syncthreads();
    for (int i = t; i < n_e; i += 512)
        atomicAdd(&cnt[bb[i] >> 17], 1);
    __syncthreads();
    if (t < 128) sc[t] = cnt[t];
    __syncthreads();
    for (int off = 1; off < 128; off <<= 1) {
        int v = 0;
        if (t < 128 && t >= off) v = sc[t - off];
        __syncthreads();
        if (t < 128) sc[t] += v;
        __syncthreads();
    }
    if (t < 128) cur[t] = sc[t] - cnt[t];
    __syncthreads();
    for (int i = t; i < n_e; i += 512) {
        unsigned u = bb[i];
        int p = atomicAdd(&cur[u >> 17], 1);
        eL[p] = u;
    }
    __syncthreads();

    int lane = t & 63;
    int wv = t >> 6;
    int half = lane >> 5;
    int gid = (lane >> 4) & 1;
    int hp = lane & 15;
    const float2 a2 = ((const float2*)att)[hp];
    const float2 b2 = ((const float2*)bias)[hp];
    int lg0 = batch[bin * FBIN_SZ];

    for (int nl = wv * 2 + half; nl < FBIN_SZ; nl += 16) {
        int n = bin * FBIN_SZ + nl;
        int e0 = (nl > 0) ? sc[nl - 1] : 0;
        int e1 = sc[nl];
        const float2 xr2 = ((const float2*)(xr + (size_t)n * H_DIM))[hp];
        const float2 xl2 = __half22float2(((const __half2*)(xl16 + (size_t)n * H_DIM))[hp]);

        float vx = xl2.x + xr2.x; vx = fmaxf(vx, vx * NEG);
        float vy = xl2.y + xr2.y; vy = fmaxf(vy, vy * NEG);
        float pr = vx * a2.x; pr = fmaf(vy, a2.y, pr);
        pr += __shfl_xor(pr, 1); pr += __shfl_xor(pr, 2);
        pr += __shfl_xor(pr, 4); pr += __shfl_xor(pr, 8);
        float z = 0.f; float2 acc = make_float2(0.f, 0.f);
        if (gid == 0) {
            float p = __expf(fminf(pr, 70.f));
            z = p; acc.x = p * xl2.x; acc.y = p * xl2.y;
        }

        int j = e0 + gid;
        for (; j + 2 < e1; j += 4) {          // 2-deep unroll per stream
            unsigned uA = eL[j], uB = eL[j + 2];
            int sA = (int)(uA & 0x1FFFFu), sB = (int)(uB & 0x1FFFFu);
            float2 xA = __half22float2(((const __half2*)(xl16 + (size_t)sA * H_DIM))[hp]);
            float2 xB = __half22float2(((const __half2*)(xl16 + (size_t)sB * H_DIM))[hp]);
            float ax = xA.x + xr2.x; ax = fmaxf(ax, ax * NEG);
            float ay = xA.y + xr2.y; ay = fmaxf(ay, ay * NEG);
            float bx = xB.x + xr2.x; bx = fmaxf(bx, bx * NEG);
            float by = xB.y + xr2.y; by = fmaxf(by, by * NEG);
            float pA = ax * a2.x; pA = fmaf(ay, a2.y, pA);
            float pB = bx * a2.x; pB = fmaf(by, a2.y, pB);
            pA += __shfl_xor(pA, 1); pB += __shfl_xor(pB, 1);
            pA += __shfl_xor(pA, 2); pB += __shfl_xor(pB, 2);
            pA += __shfl_xor(pA, 4); pB += __shfl_xor(pB, 4);
            pA += __shfl_xor(pA, 8); pB += __shfl_xor(pB, 8);
            float eA = __expf(fminf(pA, 70.f));
            float eB = __expf(fminf(pB, 70.f));
            z += eA + eB;
            acc.x = fmaf(eA, xA.x, acc.x); acc.y = fmaf(eA, xA.y, acc.y);
            acc.x = fmaf(eB, xB.x, acc.x); acc.y = fmaf(eB, xB.y, acc.y);
        }
        for (; j < e1; j += 2) {
            unsigned u = eL[j];
            int s = (int)(u & 0x1FFFFu);
            float2 xs2 = __half22float2(((const __half2*)(xl16 + (size_t)s * H_DIM))[hp]);
            float ex = xs2.x + xr2.x; ex = fmaxf(ex, ex * NEG);
            float ey = xs2.y + xr2.y; ey = fmaxf(ey, ey * NEG);
            float pp = ex * a2.x; pp = fmaf(ey, a2.y, pp);
            pp += __shfl_xor(pp, 1); pp += __shfl_xor(pp, 2);
            pp += __shfl_xor(pp, 4); pp += __shfl_xor(pp, 8);
            float p = __expf(fminf(pp, 70.f));
            z += p;
            acc.x = fmaf(p, xs2.x, acc.x);
            acc.y = fmaf(p, xs2.y, acc.y);
        }

        z += __shfl_xor(z, 16);
        acc.x += __shfl_xor(acc.x, 16);
        acc.y += __shfl_xor(acc.y, 16);

        if (gid == 0) {
            float inv = 1.f / z;
            float ox = fmaf(acc.x, inv, b2.x);
            float oy = fmaf(acc.y, inv, b2.y);
            int gi = batch[n] - lg0;
            atomicMax(&lmax[gi * 32 + hp * 2 + 0], fenc(ox));
            atomicMax(&lmax[gi * 32 + hp * 2 + 1], fenc(oy));
        }
    }
    __syncthreads();
    if (t < 64) {
        int g = lg0 + (t >> 5);
        int glast = batch[bin * FBIN_SZ + FBIN_SZ - 1];
        if (g <= glast) atomicMax(&gu[g * H_DIM + (t & 31)], lmax[t]);
    }
}

// K3: MLP head, one graph per block (256 blocks), h1/h2 in LDS, 4-way
// K-slice ILP in the W2 stage.
__global__ __launch_bounds__(512) void k_head(
    const unsigned* __restrict__ gu, const float* __restrict__ W1,
    const float* __restrict__ b1, const float* __restrict__ W2,
    const float* __restrict__ b2, const float* __restrict__ W3,
    const float* __restrict__ b3, float* __restrict__ out)
{
    __shared__ float gs[H_DIM];
    __shared__ float h1s[1024];
    __shared__ float h2s[512];
    int b = blockIdx.x, t = threadIdx.x;
    if (t < H_DIM) gs[t] = fdec(gu[b * H_DIM + t]);
    __syncthreads();
    #pragma unroll
    for (int jj = 0; jj < 2; ++jj) {        // h1: 1024 cols
        int j = jj * 512 + t;
        float a = b1[j];
        #pragma unroll
        for (int k = 0; k < H_DIM; ++k) a = fmaf(gs[k], W1[k * 1024 + j], a);
        h1s[j] = fmaxf(a, 0.f);
    }
    __syncthreads();
    {                                        // h2: 512 cols, 4 K-slices ILP
        float a0 = 0.f, a1 = 0.f, a2 = 0.f, a3 = 0.f;
        #pragma unroll 4
        for (int k = 0; k < 256; ++k) {
            a0 = fmaf(h1s[k      ], W2[(size_t)(k      ) * 512 + t], a0);
            a1 = fmaf(h1s[k + 256], W2[(size_t)(k + 256) * 512 + t], a1);
            a2 = fmaf(h1s[k + 512], W2[(size_t)(k + 512) * 512 + t], a2);
            a3 = fmaf(h1s[k + 768], W2[(size_t)(k + 768) * 512 + t], a3);
        }
        h2s[t] = fmaxf((a0 + a1) + (a2 + a3) + b2[t], 0.f);
    }
    __syncthreads();
    if (t < 256) {                           // out: 4 classes x 64 lanes
        int c = t >> 6, lane = t & 63;
        float a = 0.f;
        #pragma unroll
        for (int k = lane; k < 512; k += 64)
            a = fmaf(h2s[k], W3[k * 4 + c], a);
        for (int off = 32; off; off >>= 1) a += __shfl_down(a, off);
        if (lane == 0) out[b * 4 + c] = a + b3[c];
    }
}

extern "C" void kernel_launch(void* const* d_in, const int* in_sizes, int n_in,
                              void* d_out, int out_size, void* d_ws, size_t ws_size,
                              hipStream_t stream)
{
    const float* x     = (const float*)d_in[0];
    const int*   ei    = (const int*)d_in[1];
    const int*   batch = (const int*)d_in[2];
    const float* Wl    = (const float*)d_in[3];
    const float* Wr    = (const float*)d_in[4];
    const float* att   = (const float*)d_in[5];
    const float* bias  = (const float*)d_in[6];
    const float* W1    = (const float*)d_in[7];
    const float* b1    = (const float*)d_in[8];
    const float* W2    = (const float*)d_in[9];
    const float* b2    = (const float*)d_in[10];
    const float* W3    = (const float*)d_in[11];
    const float* b3    = (const float*)d_in[12];
    float* out = (float*)d_out;

    // workspace layout (~36 MB)
    __half*   xl16   = (__half*)d_ws;                              // 3.2M halfs (6.4 MB)
    float*    xr     = (float*)(xl16 + (size_t)N_NODES * H_DIM);   // 3.2M f
    unsigned* binbuf = (unsigned*)(xr + (size_t)N_NODES * H_DIM);  // 1000*4096
    int*      bcnt   = (int*)(binbuf + (size_t)N_FBIN * BIN_CAP);  // 16384 [memset]
    unsigned* gu     = (unsigned*)(bcnt + N_FBIN * CPAD);          // 8192  [memset]

    hipMemsetAsync(bcnt, 0, (size_t)(N_FBIN * CPAD + B_GR * H_DIM) * sizeof(int), stream);

    k_fused<<<PART_NBLK + LIN_BLK, 1024, 0, stream>>>(
        ei, bcnt, binbuf, x, Wl, Wr, xl16, xr);
    k_aggregate<<<N_FBIN, 512, 0, stream>>>(binbuf, bcnt, xl16, xr, att, bias, batch, gu);
    k_head<<<B_GR, 512, 0, stream>>>(gu, W1, b1, W2, b2, W3, b3, out);
}

// Round 17
// 156.543 us; speedup vs baseline: 1.2623x; 1.0816x over previous
//
#include <hip/hip_runtime.h>
#include <hip/hip_fp16.h>

#define N_NODES 100000
#define N_EDGES 3200000
#define F_IN    128
#define H_DIM   32
#define B_GR    256
#define NEG     0.2f

#define FBIN_SZ  125
#define N_FBIN   (N_NODES / FBIN_SZ)        // 800
#define BIN_CAP  5120                        // mean 4000, +17.7 sigma
#define CPAD     16                          // bcnt 64B padding
#define PART_T   1024
#define EPB_R    8                           // int4 rounds per thread (re-read)
#define EPB_G    (PART_T * EPB_R)            // 32768 edges/block
#define PART_NBLK ((N_EDGES / 4 + EPB_G - 1) / EPB_G)   // 98
#define LIN_BLK  ((N_NODES + 63) / 64)       // 1563 (64 nodes/block)

// ---- monotonic float<->uint encoding for atomicMax on floats ----
__device__ __forceinline__ unsigned fenc(float f) {
    unsigned u = __float_as_uint(f);
    return (u & 0x80000000u) ? ~u : (u | 0x80000000u);
}
__device__ __forceinline__ float fdec(unsigned u) {
    return (u & 0x80000000u) ? __uint_as_float(u & 0x7FFFFFFFu)
                             : __uint_as_float(~u);
}

// K1: fat kernel. Blocks [0, PART_NBLK): two-pass edge binning (32768
// edges/block; pass1 reads dst only -> LDS hist; one global atomic per
// touched bin; pass2 re-reads ei (L2-hot), direct-writes ~full-line runs).
// Blocks [PART_NBLK, +LIN_BLK): xl16 = fp16(x@Wl), xr = x@Wr as
// 4 x 256-thread quarters sharing W tiles. Independent -> co-scheduled.
__global__ __launch_bounds__(1024) void k_fused(
    const int* __restrict__ ei, int* __restrict__ bcnt, unsigned* __restrict__ binbuf,
    const float* __restrict__ x, const float* __restrict__ Wl,
    const float* __restrict__ Wr, __half* __restrict__ xl16, float* __restrict__ xr)
{
    __shared__ __align__(16) float smem[16384];   // 64 KB union
    int t = threadIdx.x;

    if (blockIdx.x < PART_NBLK) {
        // ---------------- edge binning (two-pass, re-read) ----------------
        int* lcnt = (int*)smem;           // 1024 ints (800 used)
        int* cur  = lcnt + 1024;          // 1024 ints
        lcnt[t] = 0;
        __syncthreads();
        int g0 = blockIdx.x * EPB_G;
        const int4* dsrc = (const int4*)(ei + N_EDGES);
        const int4* ssrc = (const int4*)ei;
        #pragma unroll
        for (int r = 0; r < EPB_R; ++r) {
            int i = g0 + r * PART_T + t;
            if (i < N_EDGES / 4) {
                int4 d = dsrc[i];
                atomicAdd(&lcnt[d.x / FBIN_SZ], 1);
                atomicAdd(&lcnt[d.y / FBIN_SZ], 1);
                atomicAdd(&lcnt[d.z / FBIN_SZ], 1);
                atomicAdd(&lcnt[d.w / FBIN_SZ], 1);
            }
        }
        __syncthreads();
        if (t < N_FBIN) {
            int c = lcnt[t];
            if (c > 0) cur[t] = atomicAdd(&bcnt[t * CPAD], c);
        }
        __syncthreads();
        #pragma unroll
        for (int r = 0; r < EPB_R; ++r) {
            int i = g0 + r * PART_T + t;
            if (i < N_EDGES / 4) {
                int4 s = ssrc[i];
                int4 d = dsrc[i];
                int b, p;
                b = d.x / FBIN_SZ; p = atomicAdd(&cur[b], 1);
                binbuf[(size_t)b * BIN_CAP + p] = ((unsigned)(d.x - b * FBIN_SZ) << 17) | (unsigned)s.x;
                b = d.y / FBIN_SZ; p = atomicAdd(&cur[b], 1);
                binbuf[(size_t)b * BIN_CAP + p] = ((unsigned)(d.y - b * FBIN_SZ) << 17) | (unsigned)s.y;
                b = d.z / FBIN_SZ; p = atomicAdd(&cur[b], 1);
                binbuf[(size_t)b * BIN_CAP + p] = ((unsigned)(d.z - b * FBIN_SZ) << 17) | (unsigned)s.z;
                b = d.w / FBIN_SZ; p = atomicAdd(&cur[b], 1);
                binbuf[(size_t)b * BIN_CAP + p] = ((unsigned)(d.w - b * FBIN_SZ) << 17) | (unsigned)s.w;
            }
        }
    } else {
        // ---------------- linear: xl16/xr ----------------
        float* Wls = smem;            // 4096
        float* Wrs = smem + 4096;     // 4096
        float* xsb = smem + 8192;     // 4 x 2048
        int blk = blockIdx.x - PART_NBLK;
        for (int i = t; i < F_IN * H_DIM; i += 1024) { Wls[i] = Wl[i]; Wrs[i] = Wr[i]; }
        int q = t >> 8, tq = t & 255;
        size_t base = (size_t)blk * 64 + q * 16;
        bool act = base < N_NODES;     // quarters are 16-aligned; all-or-nothing
        float* xs = xsb + q * 2048;
        if (act) {
            const float4* xg = (const float4*)(x + base * F_IN);
            float4* xs4 = (float4*)xs;
            xs4[tq] = xg[tq];
            xs4[tq + 256] = xg[tq + 256];
        }
        __syncthreads();
        if (act) {
            int nl = tq >> 5, h = tq & 31;
            float al0 = 0.f, ar0 = 0.f, al1 = 0.f, ar1 = 0.f;
            const float4* xa4 = (const float4*)(xs + nl * F_IN);
            const float4* xb4 = (const float4*)(xs + (nl + 8) * F_IN);
            #pragma unroll 8
            for (int f4 = 0; f4 < 32; ++f4) {
                float4 xa = xa4[f4], xb = xb4[f4];
                int fb = f4 * 4;
                float w;
                w = Wls[(fb + 0) * 32 + h]; al0 = fmaf(xa.x, w, al0); al1 = fmaf(xb.x, w, al1);
                w = Wls[(fb + 1) * 32 + h]; al0 = fmaf(xa.y, w, al0); al1 = fmaf(xb.y, w, al1);
                w = Wls[(fb + 2) * 32 + h]; al0 = fmaf(xa.z, w, al0); al1 = fmaf(xb.z, w, al1);
                w = Wls[(fb + 3) * 32 + h]; al0 = fmaf(xa.w, w, al0); al1 = fmaf(xb.w, w, al1);
                w = Wrs[(fb + 0) * 32 + h]; ar0 = fmaf(xa.x, w, ar0); ar1 = fmaf(xb.x, w, ar1);
                w = Wrs[(fb + 1) * 32 + h]; ar0 = fmaf(xa.y, w, ar0); ar1 = fmaf(xb.y, w, ar1);
                w = Wrs[(fb + 2) * 32 + h]; ar0 = fmaf(xa.z, w, ar0); ar1 = fmaf(xb.z, w, ar1);
                w = Wrs[(fb + 3) * 32 + h]; ar0 = fmaf(xa.w, w, ar0); ar1 = fmaf(xb.w, w, ar1);
            }
            size_t n0 = base + nl, n1 = base + nl + 8;
            xl16[n0 * 32 + h] = __float2half(al0); xr[n0 * 32 + h] = ar0;
            xl16[n1 * 32 + h] = __float2half(al1); xr[n1 * 32 + h] = ar1;
        }
    }
}

// K2: per-bin in-LDS CSR build + fused score/softmax/aggregate/pool.
// Block = one bin (125 dst nodes, <=5120 edges). Phase 2: 16 lanes per node
// (2 streams x 8 lanes); lane = h-quad (4 h's via one 8B fp16 load). Score:
// in-lane 4-wide dot + 3-step shfl butterfly within 8 lanes; 8 edges in
// flight per wave. 2-deep unroll per stream. All math f32.
__global__ __launch_bounds__(512) void k_aggregate(
    const unsigned* __restrict__ binbuf, const int* __restrict__ bcnt,
    const __half* __restrict__ xl16, const float* __restrict__ xr,
    const float* __restrict__ att, const float* __restrict__ bias,
    const int* __restrict__ batch, unsigned* __restrict__ gu)
{
    __shared__ unsigned eL[BIN_CAP];      // 20 KB sorted edge list
    __shared__ int cnt[128];
    __shared__ int sc[128];
    __shared__ int cur[128];
    __shared__ unsigned lmax[64];         // bin spans <= 2 graphs (125 < 390)
    int t = threadIdx.x;
    int bin = blockIdx.x;
    int n_e = bcnt[bin * CPAD];
    const unsigned* bb = binbuf + (size_t)bin * BIN_CAP;

    if (t < 128) cnt[t] = 0;
    if (t < 64) lmax[t] = 0u;             // encodes -inf
    __syncthreads();
    for (int i = t; i < n_e; i += 512)
        atomicAdd(&cnt[bb[i] >> 17], 1);
    __syncthreads();
    if (t < 128) sc[t] = cnt[t];
    __syncthreads();
    for (int off = 1; off < 128; off <<= 1) {
        int v = 0;
        if (t < 128 && t >= off) v = sc[t - off];
        __syncthreads();
        if (t < 128) sc[t] += v;
        __syncthreads();
    }
    if (t < 128) cur[t] = sc[t] - cnt[t];
    __syncthreads();
    for (int i = t; i < n_e; i += 512) {
        unsigned u = bb[i];
        int p = atomicAdd(&cur[u >> 17], 1);
        eL[p] = u;
    }
    __syncthreads();

    int lane = t & 63;
    int wv = t >> 6;                      // wave 0..7
    int ns = (lane >> 4) & 3;             // node slot in wave (4 nodes/wave)
    int stream = (lane >> 3) & 1;         // edge-stream 0/1
    int oct = lane & 7;                   // h-quad: h = 4*oct .. 4*oct+3
    const float4 a4 = ((const float4*)att)[oct];
    const float4 b4 = ((const float4*)bias)[oct];
    int lg0 = batch[bin * FBIN_SZ];

    for (int nl = wv * 4 + ns; nl < FBIN_SZ; nl += 32) {
        int n = bin * FBIN_SZ + nl;
        int e0 = (nl > 0) ? sc[nl - 1] : 0;
        int e1 = sc[nl];
        const float4 xr4 = ((const float4*)(xr + (size_t)n * H_DIM))[oct];
        float2 raw = ((const float2*)(xl16 + (size_t)n * H_DIM))[oct];
        float2 sf0 = __half22float2(*(__half2*)&raw.x);
        float2 sf1 = __half22float2(*(__half2*)&raw.y);

        float z = 0.f;
        float4 acc = make_float4(0.f, 0.f, 0.f, 0.f);
        {   // self-loop (credited by stream 0)
            float vx = sf0.x + xr4.x; vx = fmaxf(vx, vx * NEG);
            float vy = sf0.y + xr4.y; vy = fmaxf(vy, vy * NEG);
            float vz = sf1.x + xr4.z; vz = fmaxf(vz, vz * NEG);
            float vw = sf1.y + xr4.w; vw = fmaxf(vw, vw * NEG);
            float pr = vx * a4.x;
            pr = fmaf(vy, a4.y, pr);
            pr = fmaf(vz, a4.z, pr);
            pr = fmaf(vw, a4.w, pr);
            pr += __shfl_xor(pr, 1);
            pr += __shfl_xor(pr, 2);
            pr += __shfl_xor(pr, 4);
            if (stream == 0) {
                float p = __expf(fminf(pr, 70.f));
                z = p;
                acc = make_float4(p * sf0.x, p * sf0.y, p * sf1.x, p * sf1.y);
            }
        }

        int j = e0 + stream;
        for (; j + 2 < e1; j += 4) {          // 2-deep unroll per stream
            unsigned uA = eL[j], uB = eL[j + 2];
            int sA = (int)(uA & 0x1FFFFu), sB = (int)(uB & 0x1FFFFu);
            float2 rA = ((const float2*)(xl16 + (size_t)sA * H_DIM))[oct];
            float2 rB = ((const float2*)(xl16 + (size_t)sB * H_DIM))[oct];
            float2 A0 = __half22float2(*(__half2*)&rA.x);
            float2 A1 = __half22float2(*(__half2*)&rA.y);
            float2 B0 = __half22float2(*(__half2*)&rB.x);
            float2 B1 = __half22float2(*(__half2*)&rB.y);
            float pA, pB;
            {
                float vx = A0.x + xr4.x; vx = fmaxf(vx, vx * NEG);
                float vy = A0.y + xr4.y; vy = fmaxf(vy, vy * NEG);
                float vz = A1.x + xr4.z; vz = fmaxf(vz, vz * NEG);
                float vw = A1.y + xr4.w; vw = fmaxf(vw, vw * NEG);
                pA = vx * a4.x; pA = fmaf(vy, a4.y, pA);
                pA = fmaf(vz, a4.z, pA); pA = fmaf(vw, a4.w, pA);
            }
            {
                float vx = B0.x + xr4.x; vx = fmaxf(vx, vx * NEG);
                float vy = B0.y + xr4.y; vy = fmaxf(vy, vy * NEG);
                float vz = B1.x + xr4.z; vz = fmaxf(vz, vz * NEG);
                float vw = B1.y + xr4.w; vw = fmaxf(vw, vw * NEG);
                pB = vx * a4.x; pB = fmaf(vy, a4.y, pB);
                pB = fmaf(vz, a4.z, pB); pB = fmaf(vw, a4.w, pB);
            }
            pA += __shfl_xor(pA, 1); pB += __shfl_xor(pB, 1);
            pA += __shfl_xor(pA, 2); pB += __shfl_xor(pB, 2);
            pA += __shfl_xor(pA, 4); pB += __shfl_xor(pB, 4);
            float eA = __expf(fminf(pA, 70.f));
            float eB = __expf(fminf(pB, 70.f));
            z += eA + eB;
            acc.x = fmaf(eA, A0.x, acc.x); acc.y = fmaf(eA, A0.y, acc.y);
            acc.z = fmaf(eA, A1.x, acc.z); acc.w = fmaf(eA, A1.y, acc.w);
            acc.x = fmaf(eB, B0.x, acc.x); acc.y = fmaf(eB, B0.y, acc.y);
            acc.z = fmaf(eB, B1.x, acc.z); acc.w = fmaf(eB, B1.y, acc.w);
        }
        for (; j < e1; j += 2) {
            unsigned u = eL[j];
            int s = (int)(u & 0x1FFFFu);
            float2 rS = ((const float2*)(xl16 + (size_t)s * H_DIM))[oct];
            float2 S0 = __half22float2(*(__half2*)&rS.x);
            float2 S1 = __half22float2(*(__half2*)&rS.y);
            float vx = S0.x + xr4.x; vx = fmaxf(vx, vx * NEG);
            float vy = S0.y + xr4.y; vy = fmaxf(vy, vy * NEG);
            float vz = S1.x + xr4.z; vz = fmaxf(vz, vz * NEG);
            float vw = S1.y + xr4.w; vw = fmaxf(vw, vw * NEG);
            float pp = vx * a4.x; pp = fmaf(vy, a4.y, pp);
            pp = fmaf(vz, a4.z, pp); pp = fmaf(vw, a4.w, pp);
            pp += __shfl_xor(pp, 1);
            pp += __shfl_xor(pp, 2);
            pp += __shfl_xor(pp, 4);
            float p = __expf(fminf(pp, 70.f));
            z += p;
            acc.x = fmaf(p, S0.x, acc.x); acc.y = fmaf(p, S0.y, acc.y);
            acc.z = fmaf(p, S1.x, acc.z); acc.w = fmaf(p, S1.y, acc.w);
        }

        // merge the two 8-lane streams
        z += __shfl_xor(z, 8);
        acc.x += __shfl_xor(acc.x, 8);
        acc.y += __shfl_xor(acc.y, 8);
        acc.z += __shfl_xor(acc.z, 8);
        acc.w += __shfl_xor(acc.w, 8);

        if (stream == 0) {
            float inv = 1.f / z;
            int gi = batch[n] - lg0;      // 0 or 1
            int base = gi * 32 + oct * 4;
            atomicMax(&lmax[base + 0], fenc(fmaf(acc.x, inv, b4.x)));
            atomicMax(&lmax[base + 1], fenc(fmaf(acc.y, inv, b4.y)));
            atomicMax(&lmax[base + 2], fenc(fmaf(acc.z, inv, b4.z)));
            atomicMax(&lmax[base + 3], fenc(fmaf(acc.w, inv, b4.w)));
        }
    }
    __syncthreads();
    if (t < 64) {                         // flush <=2 graphs to global
        int g = lg0 + (t >> 5);
        int glast = batch[bin * FBIN_SZ + FBIN_SZ - 1];
        if (g <= glast) atomicMax(&gu[g * H_DIM + (t & 31)], lmax[t]);
    }
}

// K3: MLP head, one graph per block (256 blocks), h1/h2 in LDS, 4-way
// K-slice ILP in the W2 stage.
__global__ __launch_bounds__(512) void k_head(
    const unsigned* __restrict__ gu, const float* __restrict__ W1,
    const float* __restrict__ b1, const float* __restrict__ W2,
    const float* __restrict__ b2, const float* __restrict__ W3,
    const float* __restrict__ b3, float* __restrict__ out)
{
    __shared__ float gs[H_DIM];
    __shared__ float h1s[1024];
    __shared__ float h2s[512];
    int b = blockIdx.x, t = threadIdx.x;
    if (t < H_DIM) gs[t] = fdec(gu[b * H_DIM + t]);
    __syncthreads();
    #pragma unroll
    for (int jj = 0; jj < 2; ++jj) {        // h1: 1024 cols
        int j = jj * 512 + t;
        float a = b1[j];
        #pragma unroll
        for (int k = 0; k < H_DIM; ++k) a = fmaf(gs[k], W1[k * 1024 + j], a);
        h1s[j] = fmaxf(a, 0.f);
    }
    __syncthreads();
    {                                        // h2: 512 cols, 4 K-slices ILP
        float a0 = 0.f, a1 = 0.f, a2 = 0.f, a3 = 0.f;
        #pragma unroll 4
        for (int k = 0; k < 256; ++k) {
            a0 = fmaf(h1s[k      ], W2[(size_t)(k      ) * 512 + t], a0);
            a1 = fmaf(h1s[k + 256], W2[(size_t)(k + 256) * 512 + t], a1);
            a2 = fmaf(h1s[k + 512], W2[(size_t)(k + 512) * 512 + t], a2);
            a3 = fmaf(h1s[k + 768], W2[(size_t)(k + 768) * 512 + t], a3);
        }
        h2s[t] = fmaxf((a0 + a1) + (a2 + a3) + b2[t], 0.f);
    }
    __syncthreads();
    if (t < 256) {                           // out: 4 classes x 64 lanes
        int c = t >> 6, lane = t & 63;
        float a = 0.f;
        #pragma unroll
        for (int k = lane; k < 512; k += 64)
            a = fmaf(h2s[k], W3[k * 4 + c], a);
        for (int off = 32; off; off >>= 1) a += __shfl_down(a, off);
        if (lane == 0) out[b * 4 + c] = a + b3[c];
    }
}

extern "C" void kernel_launch(void* const* d_in, const int* in_sizes, int n_in,
                              void* d_out, int out_size, void* d_ws, size_t ws_size,
                              hipStream_t stream)
{
    const float* x     = (const float*)d_in[0];
    const int*   ei    = (const int*)d_in[1];
    const int*   batch = (const int*)d_in[2];
    const float* Wl    = (const float*)d_in[3];
    const float* Wr    = (const float*)d_in[4];
    const float* att   = (const float*)d_in[5];
    const float* bias  = (const float*)d_in[6];
    const float* W1    = (const float*)d_in[7];
    const float* b1    = (const float*)d_in[8];
    const float* W2    = (const float*)d_in[9];
    const float* b2    = (const float*)d_in[10];
    const float* W3    = (const float*)d_in[11];
    const float* b3    = (const float*)d_in[12];
    float* out = (float*)d_out;

    // workspace layout (~36 MB)
    __half*   xl16   = (__half*)d_ws;                              // 3.2M halfs (6.4 MB)
    float*    xr     = (float*)(xl16 + (size_t)N_NODES * H_DIM);   // 3.2M f
    unsigned* binbuf = (unsigned*)(xr + (size_t)N_NODES * H_DIM);  // 800*5120
    int*      bcnt   = (int*)(binbuf + (size_t)N_FBIN * BIN_CAP);  // 12800 [memset]
    unsigned* gu     = (unsigned*)(bcnt + N_FBIN * CPAD);          // 8192  [memset]

    hipMemsetAsync(bcnt, 0, (size_t)(N_FBIN * CPAD + B_GR * H_DIM) * sizeof(int), stream);

    k_fused<<<PART_NBLK + LIN_BLK, 1024, 0, stream>>>(
        ei, bcnt, binbuf, x, Wl, Wr, xl16, xr);
    k_aggregate<<<N_FBIN, 512, 0, stream>>>(binbuf, bcnt, xl16, xr, att, bias, batch, gu);
    k_head<<<B_GR, 512, 0, stream>>>(gu, W1, b1, W2, b2, W3, b3, out);
}